// Round 1
// baseline (937.560 us; speedup 1.0000x reference)
//
#include <hip/hip_runtime.h>

#define NFEAT 128

// ---------------- CSR build ----------------

__global__ void hist_kernel(const int* __restrict__ dst, int* __restrict__ cnt, int nE) {
    int i = blockIdx.x * blockDim.x + threadIdx.x;
    if (i < nE) atomicAdd(&cnt[dst[i]], 1);
}

// Single-block exclusive scan over node degrees.
// Writes row_ptr[0..n], rewrites cnt[i] = exclusive prefix (fill cursor),
// and inv_deg[i] = 1/max(deg,1).
__global__ void scan_kernel(int* __restrict__ cnt, int* __restrict__ row_ptr,
                            float* __restrict__ inv_deg, int n) {
    __shared__ int buf[1024];
    __shared__ int carry_s;
    int tid = threadIdx.x;
    if (tid == 0) carry_s = 0;
    __syncthreads();
    for (int base = 0; base < n; base += 1024) {
        int i = base + tid;
        int d = (i < n) ? cnt[i] : 0;
        buf[tid] = d;
        __syncthreads();
        for (int off = 1; off < 1024; off <<= 1) {
            int v = (tid >= off) ? buf[tid - off] : 0;
            __syncthreads();
            buf[tid] += v;
            __syncthreads();
        }
        int incl = buf[tid];
        int excl = incl - d;
        int carry = carry_s;
        if (i < n) {
            row_ptr[i] = carry + excl;
            cnt[i]     = carry + excl;
            inv_deg[i] = 1.0f / (float)(d > 1 ? d : 1);
        }
        __syncthreads();
        if (tid == 1023) carry_s = carry + incl;
        __syncthreads();
    }
    if (tid == 0) row_ptr[n] = carry_s;
}

__global__ void fill_kernel(const int* __restrict__ src, const int* __restrict__ dst,
                            int* __restrict__ cnt, int* __restrict__ col_idx, int nE) {
    int i = blockIdx.x * blockDim.x + threadIdx.x;
    if (i < nE) {
        int pos = atomicAdd(&cnt[dst[i]], 1);
        col_idx[pos] = src[i];
    }
}

// ---------------- mean aggregation (CSR gather) ----------------
// 32 lanes per node, float4 each -> 128 floats/row. 8 nodes per 256-thread block.
__global__ void agg_kernel(const float* __restrict__ in, const int* __restrict__ row_ptr,
                           const int* __restrict__ col_idx, const float* __restrict__ inv_deg,
                           float* __restrict__ agg, int n) {
    int lane = threadIdx.x & 31;
    int node = blockIdx.x * 8 + (threadIdx.x >> 5);
    if (node >= n) return;
    int beg = row_ptr[node], end = row_ptr[node + 1];
    float4 acc = make_float4(0.f, 0.f, 0.f, 0.f);
    for (int e = beg; e < end; ++e) {
        int s = col_idx[e];
        float4 v = ((const float4*)(in + (size_t)s * NFEAT))[lane];
        acc.x += v.x; acc.y += v.y; acc.z += v.z; acc.w += v.w;
    }
    float sc = inv_deg[node];
    acc.x *= sc; acc.y *= sc; acc.z *= sc; acc.w *= sc;
    ((float4*)(agg + (size_t)node * NFEAT))[lane] = acc;
}

// ---------------- fused GEMM: out = agg@Wl + x@Wr + b (+ReLU) ----------------

__device__ __forceinline__ void fma4(float4& acc, float a, const float4 w) {
    acc.x += a * w.x; acc.y += a * w.y; acc.z += a * w.z; acc.w += a * w.w;
}

template<int NOUT, bool RELU>
__global__ void gemm_kernel(const float* __restrict__ xin, const float* __restrict__ agg,
                            const float* __restrict__ Wl, const float* __restrict__ Wr,
                            const float* __restrict__ bias, float* __restrict__ out, int n) {
    constexpr int CG = NOUT / 4;               // float4 col-groups per row
    int cg   = threadIdx.x;                    // [0, CG)
    int node = blockIdx.x * blockDim.y + threadIdx.y;
    if (node >= n) return;
    const float4* A  = (const float4*)(agg + (size_t)node * NFEAT);
    const float4* X  = (const float4*)(xin + (size_t)node * NFEAT);
    const float4* wl = (const float4*)Wl;      // [K][CG] of float4
    const float4* wr = (const float4*)Wr;
    float4 acc = ((const float4*)bias)[cg];
    #pragma unroll 8
    for (int k4 = 0; k4 < NFEAT / 4; ++k4) {
        float4 a4 = A[k4];
        float4 x4 = X[k4];
        fma4(acc, a4.x, wl[(4 * k4 + 0) * CG + cg]);
        fma4(acc, a4.y, wl[(4 * k4 + 1) * CG + cg]);
        fma4(acc, a4.z, wl[(4 * k4 + 2) * CG + cg]);
        fma4(acc, a4.w, wl[(4 * k4 + 3) * CG + cg]);
        fma4(acc, x4.x, wr[(4 * k4 + 0) * CG + cg]);
        fma4(acc, x4.y, wr[(4 * k4 + 1) * CG + cg]);
        fma4(acc, x4.z, wr[(4 * k4 + 2) * CG + cg]);
        fma4(acc, x4.w, wr[(4 * k4 + 3) * CG + cg]);
    }
    if (RELU) {
        acc.x = fmaxf(acc.x, 0.f); acc.y = fmaxf(acc.y, 0.f);
        acc.z = fmaxf(acc.z, 0.f); acc.w = fmaxf(acc.w, 0.f);
    }
    ((float4*)(out + (size_t)node * NOUT))[cg] = acc;
}

extern "C" void kernel_launch(void* const* d_in, const int* in_sizes, int n_in,
                              void* d_out, int out_size, void* d_ws, size_t ws_size,
                              hipStream_t stream) {
    const float* x   = (const float*)d_in[0];
    const int*   ei  = (const int*)d_in[1];
    const float* Wl0 = (const float*)d_in[2];
    const float* Wr0 = (const float*)d_in[3];
    const float* b0  = (const float*)d_in[4];
    const float* Wl1 = (const float*)d_in[5];
    const float* Wr1 = (const float*)d_in[6];
    const float* b1  = (const float*)d_in[7];
    const float* Wl2 = (const float*)d_in[8];
    const float* Wr2 = (const float*)d_in[9];
    const float* b2  = (const float*)d_in[10];

    const int nN = in_sizes[0] / NFEAT;       // 50000
    const int nE = in_sizes[1] / 2;           // 800000
    const int* src = ei;
    const int* dst = ei + nE;

    // workspace layout (256B-aligned chunks)
    char* ws = (char*)d_ws;
    size_t off = 0;
    auto take = [&](size_t bytes) { char* p = ws + off; off += (bytes + 255) & ~(size_t)255; return p; };
    int*   cnt     = (int*)  take((size_t)nN * 4);
    int*   row_ptr = (int*)  take((size_t)(nN + 1) * 4);
    int*   col_idx = (int*)  take((size_t)nE * 4);
    float* inv_deg = (float*)take((size_t)nN * 4);
    float* aggbuf  = (float*)take((size_t)nN * NFEAT * 4);
    float* h0      = (float*)take((size_t)nN * NFEAT * 4);
    float* h1      = (float*)take((size_t)nN * NFEAT * 4);
    (void)ws_size; (void)n_in; (void)out_size;

    // CSR build (once per launch; deterministic work, fp-order-invariant layout use)
    hipMemsetAsync(cnt, 0, (size_t)nN * 4, stream);
    hist_kernel<<<(nE + 255) / 256, 256, 0, stream>>>(dst, cnt, nE);
    scan_kernel<<<1, 1024, 0, stream>>>(cnt, row_ptr, inv_deg, nN);
    fill_kernel<<<(nE + 255) / 256, 256, 0, stream>>>(src, dst, cnt, col_idx, nE);

    const int aggGrid = (nN + 7) / 8;

    // layer 0: x -> h0 (relu)
    agg_kernel<<<aggGrid, 256, 0, stream>>>(x, row_ptr, col_idx, inv_deg, aggbuf, nN);
    gemm_kernel<128, true><<<(nN + 7) / 8, dim3(32, 8), 0, stream>>>(x, aggbuf, Wl0, Wr0, b0, h0, nN);

    // layer 1: h0 -> h1 (relu)
    agg_kernel<<<aggGrid, 256, 0, stream>>>(h0, row_ptr, col_idx, inv_deg, aggbuf, nN);
    gemm_kernel<128, true><<<(nN + 7) / 8, dim3(32, 8), 0, stream>>>(h0, aggbuf, Wl1, Wr1, b1, h1, nN);

    // layer 2: h1 -> out (no relu)
    agg_kernel<<<aggGrid, 256, 0, stream>>>(h1, row_ptr, col_idx, inv_deg, aggbuf, nN);
    gemm_kernel<64, false><<<(nN + 15) / 16, dim3(16, 16), 0, stream>>>(h1, aggbuf, Wl2, Wr2, b2, (float*)d_out, nN);
}

// Round 2
// 512.517 us; speedup vs baseline: 1.8293x; 1.8293x over previous
//
#include <hip/hip_runtime.h>

#define NFEAT 128

// ---------------- CSR build ----------------

__global__ void hist_kernel(const int* __restrict__ dst, int* __restrict__ cnt, int nE) {
    int i = blockIdx.x * blockDim.x + threadIdx.x;
    if (i < nE) atomicAdd(&cnt[dst[i]], 1);
}

// Single-block exclusive scan over node degrees.
__global__ void scan_kernel(int* __restrict__ cnt, int* __restrict__ row_ptr,
                            float* __restrict__ inv_deg, int n) {
    __shared__ int buf[1024];
    __shared__ int carry_s;
    int tid = threadIdx.x;
    if (tid == 0) carry_s = 0;
    __syncthreads();
    for (int base = 0; base < n; base += 1024) {
        int i = base + tid;
        int d = (i < n) ? cnt[i] : 0;
        buf[tid] = d;
        __syncthreads();
        for (int off = 1; off < 1024; off <<= 1) {
            int v = (tid >= off) ? buf[tid - off] : 0;
            __syncthreads();
            buf[tid] += v;
            __syncthreads();
        }
        int incl = buf[tid];
        int excl = incl - d;
        int carry = carry_s;
        if (i < n) {
            row_ptr[i] = carry + excl;
            cnt[i]     = carry + excl;
            inv_deg[i] = 1.0f / (float)(d > 1 ? d : 1);
        }
        __syncthreads();
        if (tid == 1023) carry_s = carry + incl;
        __syncthreads();
    }
    if (tid == 0) row_ptr[n] = carry_s;
}

__global__ void fill_kernel(const int* __restrict__ src, const int* __restrict__ dst,
                            int* __restrict__ cnt, int* __restrict__ col_idx, int nE) {
    int i = blockIdx.x * blockDim.x + threadIdx.x;
    if (i < nE) {
        int pos = atomicAdd(&cnt[dst[i]], 1);
        col_idx[pos] = src[i];
    }
}

// ---------------- mean aggregation (CSR gather) ----------------
__global__ void agg_kernel(const float* __restrict__ in, const int* __restrict__ row_ptr,
                           const int* __restrict__ col_idx, const float* __restrict__ inv_deg,
                           float* __restrict__ agg, int n) {
    int lane = threadIdx.x & 31;
    int node = blockIdx.x * 8 + (threadIdx.x >> 5);
    if (node >= n) return;
    int beg = row_ptr[node], end = row_ptr[node + 1];
    float4 acc = make_float4(0.f, 0.f, 0.f, 0.f);
    for (int e = beg; e < end; ++e) {
        int s = col_idx[e];
        float4 v = ((const float4*)(in + (size_t)s * NFEAT))[lane];
        acc.x += v.x; acc.y += v.y; acc.z += v.z; acc.w += v.w;
    }
    float sc = inv_deg[node];
    acc.x *= sc; acc.y *= sc; acc.z *= sc; acc.w *= sc;
    ((float4*)(agg + (size_t)node * NFEAT))[lane] = acc;
}

// ---------------- LDS-staged register-blocked GEMM ----------------
// out = agg@Wl + x@Wr + b (+ReLU). Block = 256 threads (16 col-groups x 16
// node-groups). Each thread: 4 nodes x (NOUT/16) cols. M_TILE = 64 nodes.
// W chunk (32 x NOUT) and A tile (64 x 32, stride 36 for bank-free b128
// reads) staged in LDS; W loaded from L2 once per block instead of once per
// wave-node-pair.

__device__ __forceinline__ void fma4(float4& acc, float a, const float4 w) {
    acc.x += a * w.x; acc.y += a * w.y; acc.z += a * w.z; acc.w += a * w.w;
}

template<int NOUT, bool RELU>
__global__ __launch_bounds__(256) void gemm_kernel(
    const float* __restrict__ xin, const float* __restrict__ agg,
    const float* __restrict__ Wl, const float* __restrict__ Wr,
    const float* __restrict__ bias, float* __restrict__ out, int n)
{
    constexpr int KC = 32;                 // K chunk
    constexpr int NH = NOUT / 64;          // float4 col-halves per thread (2 or 1)
    constexpr int AS = 36;                 // A_lds row stride: 144B = 16B-aligned, 2-way banks
    __shared__ float Wch[KC * NOUT];
    __shared__ float Ach[64 * AS];

    const int tid = threadIdx.x;
    const int x = tid & 15;                // col group
    const int y = tid >> 4;                // node group (4 nodes each)
    const int nodeBase = blockIdx.x * 64;

    float4 acc[4][NH];
    #pragma unroll
    for (int m = 0; m < 4; ++m)
        #pragma unroll
        for (int h = 0; h < NH; ++h)
            acc[m][h] = make_float4(0.f, 0.f, 0.f, 0.f);

    const float* Aptrs[2] = {agg, xin};
    const float* Wptrs[2] = {Wl, Wr};

    for (int p = 0; p < 2; ++p) {
        const float* A = Aptrs[p];
        const float* W = Wptrs[p];
        for (int kb = 0; kb < NFEAT; kb += KC) {
            __syncthreads();               // previous chunk fully consumed
            // stage W rows [kb, kb+KC) -- contiguous KC*NOUT floats
            {
                const float4* wg = (const float4*)(W + (size_t)kb * NOUT);
                constexpr int WF4 = KC * NOUT / 4;
                #pragma unroll
                for (int i = tid; i < WF4; i += 256)
                    ((float4*)Wch)[i] = wg[i];
            }
            // stage A tile: 64 nodes x KC floats -> Ach[node*AS + k]
            {
                #pragma unroll
                for (int f = tid; f < 64 * KC / 4; f += 256) {
                    int node = f >> 3;     // 8 float4 per node
                    int k4   = f & 7;
                    int gnode = nodeBase + node;
                    float4 v = make_float4(0.f, 0.f, 0.f, 0.f);
                    if (gnode < n)
                        v = ((const float4*)(A + (size_t)gnode * NFEAT + kb))[k4];
                    *((float4*)(Ach + node * AS + k4 * 4)) = v;
                }
            }
            __syncthreads();
            // compute chunk
            #pragma unroll
            for (int k4 = 0; k4 < KC / 4; ++k4) {
                float4 a4[4];
                #pragma unroll
                for (int m = 0; m < 4; ++m)
                    a4[m] = *((const float4*)(Ach + (y * 4 + m) * AS + k4 * 4));
                #pragma unroll
                for (int kk = 0; kk < 4; ++kk) {
                    #pragma unroll
                    for (int h = 0; h < NH; ++h) {
                        float4 w = *((const float4*)(Wch + (k4 * 4 + kk) * NOUT
                                                     + h * (NOUT / 2) + x * 4));
                        #pragma unroll
                        for (int m = 0; m < 4; ++m) {
                            float a = (kk == 0) ? a4[m].x : (kk == 1) ? a4[m].y
                                    : (kk == 2) ? a4[m].z : a4[m].w;
                            fma4(acc[m][h], a, w);
                        }
                    }
                }
            }
        }
    }

    // epilogue: bias (+ReLU), write
    #pragma unroll
    for (int m = 0; m < 4; ++m) {
        int node = nodeBase + y * 4 + m;
        if (node >= n) continue;
        #pragma unroll
        for (int h = 0; h < NH; ++h) {
            float4 b4 = ((const float4*)bias)[h * (NOUT / 8) + x];
            float4 v = acc[m][h];
            v.x += b4.x; v.y += b4.y; v.z += b4.z; v.w += b4.w;
            if (RELU) {
                v.x = fmaxf(v.x, 0.f); v.y = fmaxf(v.y, 0.f);
                v.z = fmaxf(v.z, 0.f); v.w = fmaxf(v.w, 0.f);
            }
            *((float4*)(out + (size_t)node * NOUT + h * (NOUT / 2) + x * 4)) = v;
        }
    }
}

extern "C" void kernel_launch(void* const* d_in, const int* in_sizes, int n_in,
                              void* d_out, int out_size, void* d_ws, size_t ws_size,
                              hipStream_t stream) {
    const float* x   = (const float*)d_in[0];
    const int*   ei  = (const int*)d_in[1];
    const float* Wl0 = (const float*)d_in[2];
    const float* Wr0 = (const float*)d_in[3];
    const float* b0  = (const float*)d_in[4];
    const float* Wl1 = (const float*)d_in[5];
    const float* Wr1 = (const float*)d_in[6];
    const float* b1  = (const float*)d_in[7];
    const float* Wl2 = (const float*)d_in[8];
    const float* Wr2 = (const float*)d_in[9];
    const float* b2  = (const float*)d_in[10];

    const int nN = in_sizes[0] / NFEAT;       // 50000
    const int nE = in_sizes[1] / 2;           // 800000
    const int* src = ei;
    const int* dst = ei + nE;

    char* ws = (char*)d_ws;
    size_t off = 0;
    auto take = [&](size_t bytes) { char* p = ws + off; off += (bytes + 255) & ~(size_t)255; return p; };
    int*   cnt     = (int*)  take((size_t)nN * 4);
    int*   row_ptr = (int*)  take((size_t)(nN + 1) * 4);
    int*   col_idx = (int*)  take((size_t)nE * 4);
    float* inv_deg = (float*)take((size_t)nN * 4);
    float* aggbuf  = (float*)take((size_t)nN * NFEAT * 4);
    float* h0      = (float*)take((size_t)nN * NFEAT * 4);
    float* h1      = (float*)take((size_t)nN * NFEAT * 4);
    (void)ws_size; (void)n_in; (void)out_size;

    // CSR build
    hipMemsetAsync(cnt, 0, (size_t)nN * 4, stream);
    hist_kernel<<<(nE + 255) / 256, 256, 0, stream>>>(dst, cnt, nE);
    scan_kernel<<<1, 1024, 0, stream>>>(cnt, row_ptr, inv_deg, nN);
    fill_kernel<<<(nE + 255) / 256, 256, 0, stream>>>(src, dst, cnt, col_idx, nE);

    const int aggGrid  = (nN + 7) / 8;
    const int gemmGrid = (nN + 63) / 64;

    // layer 0
    agg_kernel<<<aggGrid, 256, 0, stream>>>(x, row_ptr, col_idx, inv_deg, aggbuf, nN);
    gemm_kernel<128, true><<<gemmGrid, 256, 0, stream>>>(x, aggbuf, Wl0, Wr0, b0, h0, nN);
    // layer 1
    agg_kernel<<<aggGrid, 256, 0, stream>>>(h0, row_ptr, col_idx, inv_deg, aggbuf, nN);
    gemm_kernel<128, true><<<gemmGrid, 256, 0, stream>>>(h0, aggbuf, Wl1, Wr1, b1, h1, nN);
    // layer 2
    agg_kernel<<<aggGrid, 256, 0, stream>>>(h1, row_ptr, col_idx, inv_deg, aggbuf, nN);
    gemm_kernel<64, false><<<gemmGrid, 256, 0, stream>>>(h1, aggbuf, Wl2, Wr2, b2, (float*)d_out, nN);
}

// Round 3
// 403.816 us; speedup vs baseline: 2.3217x; 1.2692x over previous
//
#include <hip/hip_runtime.h>

#define NFEAT 128

// ---------------- CSR build ----------------

__global__ void hist_kernel(const int* __restrict__ dst, int* __restrict__ cnt, int nE) {
    int i = blockIdx.x * blockDim.x + threadIdx.x;
    if (i < nE) atomicAdd(&cnt[dst[i]], 1);
}

// Decoupled scan, phase 1: per-block sums of degrees (256 elems/block).
__global__ void blocksum_kernel(const int* __restrict__ cnt, int* __restrict__ blockSum, int n) {
    int i = blockIdx.x * 256 + threadIdx.x;
    int d = (i < n) ? cnt[i] : 0;
    int lane = threadIdx.x & 63, wid = threadIdx.x >> 6;
    __shared__ int ws[4];
    int v = d;
    for (int off = 32; off; off >>= 1) v += __shfl_down(v, off);
    if (lane == 0) ws[wid] = v;
    __syncthreads();
    if (threadIdx.x == 0) blockSum[blockIdx.x] = ws[0] + ws[1] + ws[2] + ws[3];
}

// Decoupled scan, phase 2: each block sums blockSum[0..b) (nBlocks<=256 so one
// load/thread), block-local exclusive scan, writes row_ptr + fill cursor + inv_deg.
__global__ void scan_write_kernel(int* __restrict__ cnt, const int* __restrict__ blockSum,
                                  int* __restrict__ row_ptr, float* __restrict__ inv_deg,
                                  int n) {
    const int b = blockIdx.x, tid = threadIdx.x;
    const int lane = tid & 63, wid = tid >> 6;
    __shared__ int wsA[4];
    __shared__ int wsB[4];
    // block offset = sum of preceding block sums
    int v = (tid < b) ? blockSum[tid] : 0;
    for (int off = 32; off; off >>= 1) v += __shfl_down(v, off);
    if (lane == 0) wsA[wid] = v;
    // block-local scan input
    int i = b * 256 + tid;
    int d = (i < n) ? cnt[i] : 0;
    int s = d;
    for (int off = 1; off < 64; off <<= 1) {
        int t = __shfl_up(s, off);
        if (lane >= off) s += t;
    }
    if (lane == 63) wsB[wid] = s;
    __syncthreads();
    int blockOff = wsA[0] + wsA[1] + wsA[2] + wsA[3];
    int wOff = 0;
    for (int w = 0; w < wid; ++w) wOff += wsB[w];
    int excl = blockOff + wOff + s - d;
    if (i < n) {
        row_ptr[i] = excl;
        cnt[i]     = excl;                 // fill cursor
        inv_deg[i] = 1.0f / (float)(d > 1 ? d : 1);
    }
    if (i == n) row_ptr[n] = excl;
}

__global__ void fill_kernel(const int* __restrict__ src, const int* __restrict__ dst,
                            int* __restrict__ cnt, int* __restrict__ col_idx, int nE) {
    int i = blockIdx.x * blockDim.x + threadIdx.x;
    if (i < nE) {
        int pos = atomicAdd(&cnt[dst[i]], 1);
        col_idx[pos] = src[i];
    }
}

// ---------------- mean aggregation (CSR gather) ----------------
// 32 lanes per node, float4 each. Unroll-by-4 with independent accumulators
// to keep 4 gathers in flight (L2-hit latency ~200cy).
__global__ void agg_kernel(const float* __restrict__ in, const int* __restrict__ row_ptr,
                           const int* __restrict__ col_idx, const float* __restrict__ inv_deg,
                           float* __restrict__ agg, int n) {
    int lane = threadIdx.x & 31;
    int node = blockIdx.x * 8 + (threadIdx.x >> 5);
    if (node >= n) return;
    int beg = row_ptr[node], end = row_ptr[node + 1];
    float4 a0 = make_float4(0.f, 0.f, 0.f, 0.f);
    float4 a1 = make_float4(0.f, 0.f, 0.f, 0.f);
    float4 a2 = make_float4(0.f, 0.f, 0.f, 0.f);
    float4 a3 = make_float4(0.f, 0.f, 0.f, 0.f);
    int e = beg;
    for (; e + 4 <= end; e += 4) {
        int s0 = col_idx[e], s1 = col_idx[e + 1], s2 = col_idx[e + 2], s3 = col_idx[e + 3];
        float4 v0 = ((const float4*)(in + (size_t)s0 * NFEAT))[lane];
        float4 v1 = ((const float4*)(in + (size_t)s1 * NFEAT))[lane];
        float4 v2 = ((const float4*)(in + (size_t)s2 * NFEAT))[lane];
        float4 v3 = ((const float4*)(in + (size_t)s3 * NFEAT))[lane];
        a0.x += v0.x; a0.y += v0.y; a0.z += v0.z; a0.w += v0.w;
        a1.x += v1.x; a1.y += v1.y; a1.z += v1.z; a1.w += v1.w;
        a2.x += v2.x; a2.y += v2.y; a2.z += v2.z; a2.w += v2.w;
        a3.x += v3.x; a3.y += v3.y; a3.z += v3.z; a3.w += v3.w;
    }
    for (; e < end; ++e) {
        int s = col_idx[e];
        float4 v = ((const float4*)(in + (size_t)s * NFEAT))[lane];
        a0.x += v.x; a0.y += v.y; a0.z += v.z; a0.w += v.w;
    }
    float sc = inv_deg[node];
    float4 acc;
    acc.x = (a0.x + a1.x + a2.x + a3.x) * sc;
    acc.y = (a0.y + a1.y + a2.y + a3.y) * sc;
    acc.z = (a0.z + a1.z + a2.z + a3.z) * sc;
    acc.w = (a0.w + a1.w + a2.w + a3.w) * sc;
    ((float4*)(agg + (size_t)node * NFEAT))[lane] = acc;
}

// ---------------- LDS-staged register-blocked GEMM ----------------

__device__ __forceinline__ void fma4(float4& acc, float a, const float4 w) {
    acc.x += a * w.x; acc.y += a * w.y; acc.z += a * w.z; acc.w += a * w.w;
}

template<int NOUT, bool RELU>
__global__ __launch_bounds__(256) void gemm_kernel(
    const float* __restrict__ xin, const float* __restrict__ agg,
    const float* __restrict__ Wl, const float* __restrict__ Wr,
    const float* __restrict__ bias, float* __restrict__ out, int n)
{
    constexpr int KC = 32;
    constexpr int NH = NOUT / 64;
    constexpr int AS = 36;
    __shared__ float Wch[KC * NOUT];
    __shared__ float Ach[64 * AS];

    const int tid = threadIdx.x;
    const int x = tid & 15;
    const int y = tid >> 4;
    const int nodeBase = blockIdx.x * 64;

    float4 acc[4][NH];
    #pragma unroll
    for (int m = 0; m < 4; ++m)
        #pragma unroll
        for (int h = 0; h < NH; ++h)
            acc[m][h] = make_float4(0.f, 0.f, 0.f, 0.f);

    const float* Aptrs[2] = {agg, xin};
    const float* Wptrs[2] = {Wl, Wr};

    for (int p = 0; p < 2; ++p) {
        const float* A = Aptrs[p];
        const float* W = Wptrs[p];
        for (int kb = 0; kb < NFEAT; kb += KC) {
            __syncthreads();
            {
                const float4* wg = (const float4*)(W + (size_t)kb * NOUT);
                constexpr int WF4 = KC * NOUT / 4;
                #pragma unroll
                for (int i = tid; i < WF4; i += 256)
                    ((float4*)Wch)[i] = wg[i];
            }
            {
                #pragma unroll
                for (int f = tid; f < 64 * KC / 4; f += 256) {
                    int node = f >> 3;
                    int k4   = f & 7;
                    int gnode = nodeBase + node;
                    float4 v = make_float4(0.f, 0.f, 0.f, 0.f);
                    if (gnode < n)
                        v = ((const float4*)(A + (size_t)gnode * NFEAT + kb))[k4];
                    *((float4*)(Ach + node * AS + k4 * 4)) = v;
                }
            }
            __syncthreads();
            #pragma unroll
            for (int k4 = 0; k4 < KC / 4; ++k4) {
                float4 a4[4];
                #pragma unroll
                for (int m = 0; m < 4; ++m)
                    a4[m] = *((const float4*)(Ach + (y * 4 + m) * AS + k4 * 4));
                #pragma unroll
                for (int kk = 0; kk < 4; ++kk) {
                    #pragma unroll
                    for (int h = 0; h < NH; ++h) {
                        float4 w = *((const float4*)(Wch + (k4 * 4 + kk) * NOUT
                                                     + h * (NOUT / 2) + x * 4));
                        #pragma unroll
                        for (int m = 0; m < 4; ++m) {
                            float a = (kk == 0) ? a4[m].x : (kk == 1) ? a4[m].y
                                    : (kk == 2) ? a4[m].z : a4[m].w;
                            fma4(acc[m][h], a, w);
                        }
                    }
                }
            }
        }
    }

    #pragma unroll
    for (int m = 0; m < 4; ++m) {
        int node = nodeBase + y * 4 + m;
        if (node >= n) continue;
        #pragma unroll
        for (int h = 0; h < NH; ++h) {
            float4 b4 = ((const float4*)bias)[h * (NOUT / 8) + x];
            float4 v = acc[m][h];
            v.x += b4.x; v.y += b4.y; v.z += b4.z; v.w += b4.w;
            if (RELU) {
                v.x = fmaxf(v.x, 0.f); v.y = fmaxf(v.y, 0.f);
                v.z = fmaxf(v.z, 0.f); v.w = fmaxf(v.w, 0.f);
            }
            *((float4*)(out + (size_t)node * NOUT + h * (NOUT / 2) + x * 4)) = v;
        }
    }
}

extern "C" void kernel_launch(void* const* d_in, const int* in_sizes, int n_in,
                              void* d_out, int out_size, void* d_ws, size_t ws_size,
                              hipStream_t stream) {
    const float* x   = (const float*)d_in[0];
    const int*   ei  = (const int*)d_in[1];
    const float* Wl0 = (const float*)d_in[2];
    const float* Wr0 = (const float*)d_in[3];
    const float* b0  = (const float*)d_in[4];
    const float* Wl1 = (const float*)d_in[5];
    const float* Wr1 = (const float*)d_in[6];
    const float* b1  = (const float*)d_in[7];
    const float* Wl2 = (const float*)d_in[8];
    const float* Wr2 = (const float*)d_in[9];
    const float* b2  = (const float*)d_in[10];

    const int nN = in_sizes[0] / NFEAT;       // 50000
    const int nE = in_sizes[1] / 2;           // 800000
    const int* src = ei;
    const int* dst = ei + nE;

    char* ws = (char*)d_ws;
    size_t off = 0;
    auto take = [&](size_t bytes) { char* p = ws + off; off += (bytes + 255) & ~(size_t)255; return p; };
    int*   cnt      = (int*)  take((size_t)nN * 4);
    int*   row_ptr  = (int*)  take((size_t)(nN + 1) * 4);
    int*   col_idx  = (int*)  take((size_t)nE * 4);
    float* inv_deg  = (float*)take((size_t)nN * 4);
    int*   blockSum = (int*)  take(256 * 4);
    float* aggbuf   = (float*)take((size_t)nN * NFEAT * 4);
    float* h0       = (float*)take((size_t)nN * NFEAT * 4);
    float* h1       = (float*)take((size_t)nN * NFEAT * 4);
    (void)ws_size; (void)n_in; (void)out_size;

    const int scanBlocks = (nN + 255) / 256;  // 196 (<=256 required)

    // CSR build
    hipMemsetAsync(cnt, 0, (size_t)nN * 4, stream);
    hist_kernel<<<(nE + 255) / 256, 256, 0, stream>>>(dst, cnt, nE);
    blocksum_kernel<<<scanBlocks, 256, 0, stream>>>(cnt, blockSum, nN);
    scan_write_kernel<<<scanBlocks, 256, 0, stream>>>(cnt, blockSum, row_ptr, inv_deg, nN);
    fill_kernel<<<(nE + 255) / 256, 256, 0, stream>>>(src, dst, cnt, col_idx, nE);

    const int aggGrid  = (nN + 7) / 8;
    const int gemmGrid = (nN + 63) / 64;

    // layer 0
    agg_kernel<<<aggGrid, 256, 0, stream>>>(x, row_ptr, col_idx, inv_deg, aggbuf, nN);
    gemm_kernel<128, true><<<gemmGrid, 256, 0, stream>>>(x, aggbuf, Wl0, Wr0, b0, h0, nN);
    // layer 1
    agg_kernel<<<aggGrid, 256, 0, stream>>>(h0, row_ptr, col_idx, inv_deg, aggbuf, nN);
    gemm_kernel<128, true><<<gemmGrid, 256, 0, stream>>>(h0, aggbuf, Wl1, Wr1, b1, h1, nN);
    // layer 2
    agg_kernel<<<aggGrid, 256, 0, stream>>>(h1, row_ptr, col_idx, inv_deg, aggbuf, nN);
    gemm_kernel<64, false><<<gemmGrid, 256, 0, stream>>>(h1, aggbuf, Wl2, Wr2, b2, (float*)d_out, nN);
}